// Round 1
// baseline (12374.707 us; speedup 1.0000x reference)
//
#include <hip/hip_runtime.h>

#define NU 32

static constexpr int cN1 = 250000, cN2 = 500000, cN3 = 1000000, cN4 = 1500000;
static constexpr int cNR = 50000, cER = 300000;

// tanh(x) = 1 - 2/(exp(2x)+1), via v_exp_f32 + v_rcp_f32
__device__ __forceinline__ float fast_tanh(float x) {
    float e = __builtin_amdgcn_exp2f(x * 2.88539008177792681f); // exp(2x)
    return 1.0f - 2.0f * __builtin_amdgcn_rcpf(e + 1.0f);
}

// One node's MLP: concat(ROWS x 32 inputs) @ W1[ROWS*32,32] + b1 -> tanh -> @ W2[32,32] + b2
// Weights are wave-uniform -> scalar loads broadcast into v_fma.
template<int ROWS>
__device__ __forceinline__ void mlp_node(const float* const (&in)[ROWS],
    const float* __restrict__ W1, const float* __restrict__ b1,
    const float* __restrict__ W2, const float* __restrict__ b2,
    float* outp)
{
    float hid[NU];
    #pragma unroll
    for (int j = 0; j < NU; j++) hid[j] = b1[j];
    #pragma unroll
    for (int p = 0; p < ROWS; p++) {
        const float4* v4 = (const float4*)in[p];
        const float* wb = W1 + p * NU * NU;
        #pragma unroll
        for (int q = 0; q < 8; q++) {
            float4 v = v4[q];
            float xs[4] = {v.x, v.y, v.z, v.w};
            #pragma unroll
            for (int r = 0; r < 4; r++) {
                float x = xs[r];
                const float* w = wb + (q * 4 + r) * NU;
                #pragma unroll
                for (int j = 0; j < NU; j++) hid[j] = fmaf(x, w[j], hid[j]);
            }
        }
    }
    float o[NU];
    #pragma unroll
    for (int c = 0; c < NU; c++) o[c] = b2[c];
    #pragma unroll
    for (int j = 0; j < NU; j++) {
        float t = fast_tanh(hid[j]);
        const float* w = W2 + j * NU;
        #pragma unroll
        for (int c = 0; c < NU; c++) o[c] = fmaf(t, w[c], o[c]);
    }
    float4* o4 = (float4*)outp;
    #pragma unroll
    for (int q = 0; q < 8; q++)
        o4[q] = make_float4(o[4*q], o[4*q+1], o[4*q+2], o[4*q+3]);
}

// Up pass: m = [self_row | prev[i0] | prev[i1]] -> MLP -> out
__global__ __launch_bounds__(256) void up_kernel(
    const float* __restrict__ self, const float* __restrict__ prev,
    const int* __restrict__ i0, const int* __restrict__ i1,
    const float* __restrict__ W1, const float* __restrict__ b1,
    const float* __restrict__ W2, const float* __restrict__ b2,
    float* __restrict__ out, int N)
{
    int n = blockIdx.x * 256 + threadIdx.x;
    if (n >= N) return;
    int g0 = i0[n], g1 = i1[n];
    const float* in[3] = { self + (size_t)n * NU,
                           prev + (size_t)g0 * NU,
                           prev + (size_t)g1 * NU };
    mlp_node<3>(in, W1, b1, W2, b2, out + (size_t)n * NU);
}

// Down/ring MLP: m = [self_row | extra_row(same n)] -> MLP -> out (may be in-place)
__global__ __launch_bounds__(256) void down_kernel(
    const float* __restrict__ self, const float* __restrict__ extra,
    const float* __restrict__ W1, const float* __restrict__ b1,
    const float* __restrict__ W2, const float* __restrict__ b2,
    float* __restrict__ out, int N)
{
    int n = blockIdx.x * 256 + threadIdx.x;
    if (n >= N) return;
    const float* in[2] = { self + (size_t)n * NU, extra + (size_t)n * NU };
    mlp_node<2>(in, W1, b1, W2, b2, out + (size_t)n * NU);
}

// Scatter-add src row n into dst rows i0[n] and i1[n]
__global__ __launch_bounds__(256) void scatter2_kernel(
    const float* __restrict__ src, const int* __restrict__ i0,
    const int* __restrict__ i1, float* __restrict__ dst, int N)
{
    int n = blockIdx.x * 256 + threadIdx.x;
    if (n >= N) return;
    int d0 = i0[n], d1 = i1[n];
    const float4* s4 = (const float4*)(src + (size_t)n * NU);
    float v[NU];
    #pragma unroll
    for (int q = 0; q < 8; q++) {
        float4 t = s4[q];
        v[4*q] = t.x; v[4*q+1] = t.y; v[4*q+2] = t.z; v[4*q+3] = t.w;
    }
    float* p0 = dst + (size_t)d0 * NU;
    float* p1 = dst + (size_t)d1 * NU;
    #pragma unroll
    for (int j = 0; j < NU; j++) unsafeAtomicAdd(&p0[j], v[j]);
    #pragma unroll
    for (int j = 0; j < NU; j++) unsafeAtomicAdd(&p1[j], v[j]);
}

// Edge kernel: dst_rows[d[e]] += src_rows[s[e]]   (atomic)
__global__ __launch_bounds__(256) void edge_add_kernel(
    const float* __restrict__ src_rows, const int* __restrict__ sidx,
    const int* __restrict__ didx, float* __restrict__ dst_rows, int E)
{
    int e = blockIdx.x * 256 + threadIdx.x;
    if (e >= E) return;
    int s = sidx[e], d = didx[e];
    const float4* s4 = (const float4*)(src_rows + (size_t)s * NU);
    float* p = dst_rows + (size_t)d * NU;
    #pragma unroll
    for (int q = 0; q < 8; q++) {
        float4 t = s4[q];
        unsafeAtomicAdd(&p[4*q+0], t.x);
        unsafeAtomicAdd(&p[4*q+1], t.y);
        unsafeAtomicAdd(&p[4*q+2], t.z);
        unsafeAtomicAdd(&p[4*q+3], t.w);
    }
}

static inline int nblk(int n) { return (n + 255) / 256; }

extern "C" void kernel_launch(void* const* d_in, const int* in_sizes, int n_in,
                              void* d_out, int out_size, void* d_ws, size_t ws_size,
                              hipStream_t stream) {
    const float* h1 = (const float*)d_in[0];
    const float* h2 = (const float*)d_in[1];
    const float* h3 = (const float*)d_in[2];
    const float* h4 = (const float*)d_in[3];
    const float* upW1 = (const float*)d_in[4];   // (3,96,32)
    const float* upb1 = (const float*)d_in[5];   // (3,32)
    const float* upW2 = (const float*)d_in[6];   // (3,32,32)
    const float* upb2 = (const float*)d_in[7];   // (3,32)
    const float* dnW1 = (const float*)d_in[8];   // (3,64,32)
    const float* dnb1 = (const float*)d_in[9];
    const float* dnW2 = (const float*)d_in[10];  // (3,32,32)
    const float* dnb2 = (const float*)d_in[11];
    const float* rgW1 = (const float*)d_in[12];  // (64,32)
    const float* rgb1 = (const float*)d_in[13];
    const float* rgW2 = (const float*)d_in[14];  // (32,32)
    const float* rgb2 = (const float*)d_in[15];
    const int* idx2_0 = (const int*)d_in[16];
    const int* idx2_1 = (const int*)d_in[17];
    const int* idx3_0 = (const int*)d_in[18];
    const int* idx3_1 = (const int*)d_in[19];
    const int* idx4_0 = (const int*)d_in[20];
    const int* idx4_1 = (const int*)d_in[21];
    const int* ring_src = (const int*)d_in[22];
    const int* ring_dst = (const int*)d_in[23];

    float* out = (float*)d_out;
    float* o_h1 = out;                                   // 250000*32
    float* o_h2 = out + (size_t)cN1 * NU;                // 500000*32
    float* o_h3 = o_h2 + (size_t)cN2 * NU;               // 1M*32
    float* o_h4 = o_h3 + (size_t)cN3 * NU;               // 1.5M*32
    float* o_hr = o_h4 + (size_t)cN4 * NU;               // 50000*32

    float* ws = (float*)d_ws;  // one N3*32 fp32 buffer (128 MB), reused

    // ---- up pass (results land in d_out slots; h4 result is final) ----
    up_kernel<<<nblk(cN2), 256, 0, stream>>>(h2, h1, idx2_0, idx2_1,
        upW1 + 0*3072, upb1 + 0*32, upW2 + 0*1024, upb2 + 0*32, o_h2, cN2);
    up_kernel<<<nblk(cN3), 256, 0, stream>>>(h3, o_h2, idx3_0, idx3_1,
        upW1 + 1*3072, upb1 + 1*32, upW2 + 1*1024, upb2 + 1*32, o_h3, cN3);
    up_kernel<<<nblk(cN4), 256, 0, stream>>>(h4, o_h3, idx4_0, idx4_1,
        upW1 + 2*3072, upb1 + 2*32, upW2 + 2*1024, upb2 + 2*32, o_h4, cN4);

    // ---- down pass i=2 (k=4): scatter h4_final -> h_down(N3); MLP in-place on o_h3 ----
    hipMemsetAsync(ws, 0, (size_t)cN3 * NU * sizeof(float), stream);
    scatter2_kernel<<<nblk(cN4), 256, 0, stream>>>(o_h4, idx4_0, idx4_1, ws, cN4);
    down_kernel<<<nblk(cN3), 256, 0, stream>>>(o_h3, ws,
        dnW1 + 2*2048, dnb1 + 2*32, dnW2 + 2*1024, dnb2 + 2*32, o_h3, cN3);

    // ---- down pass i=1 (k=3) ----
    hipMemsetAsync(ws, 0, (size_t)cN2 * NU * sizeof(float), stream);
    scatter2_kernel<<<nblk(cN3), 256, 0, stream>>>(o_h3, idx3_0, idx3_1, ws, cN3);
    down_kernel<<<nblk(cN2), 256, 0, stream>>>(o_h2, ws,
        dnW1 + 1*2048, dnb1 + 1*32, dnW2 + 1*1024, dnb2 + 1*32, o_h2, cN2);

    // ---- down pass i=0 (k=2): self is ORIGINAL h1 input ----
    hipMemsetAsync(ws, 0, (size_t)cN1 * NU * sizeof(float), stream);
    scatter2_kernel<<<nblk(cN2), 256, 0, stream>>>(o_h2, idx2_0, idx2_1, ws, cN2);
    down_kernel<<<nblk(cN1), 256, 0, stream>>>(h1, ws,
        dnW1 + 0*2048, dnb1 + 0*32, dnW2 + 0*1024, dnb2 + 0*32, o_h1, cN1);

    // ---- ring: h_ring = segsum(h1_d[src] by dst); ring_down = scatter(h_ring[dst] at src) ----
    hipMemsetAsync(o_hr, 0, (size_t)cNR * NU * sizeof(float), stream);
    edge_add_kernel<<<nblk(cER), 256, 0, stream>>>(o_h1, ring_src, ring_dst, o_hr, cER);
    hipMemsetAsync(ws, 0, (size_t)cN1 * NU * sizeof(float), stream);
    edge_add_kernel<<<nblk(cER), 256, 0, stream>>>(o_hr, ring_dst, ring_src, ws, cER);
    down_kernel<<<nblk(cN1), 256, 0, stream>>>(o_h1, ws,
        rgW1, rgb1, rgW2, rgb2, o_h1, cN1);
}